// Round 10
// baseline (1016.717 us; speedup 1.0000x reference)
//
#include <hip/hip_runtime.h>
#include <cstddef>

#define H 300
#define RS 304            // row stride (halfs) for row-major bf16 buffers
#define MAXNB 6
#define ASTR 312          // LDS A-tile stride (halfs)

typedef __attribute__((ext_vector_type(8)))  short bf16x8;
typedef __attribute__((ext_vector_type(16))) float f32x16;

__device__ __forceinline__ float bf2f(unsigned short u) {
    return __uint_as_float(((unsigned int)u) << 16);
}
__device__ __forceinline__ unsigned short f2bf(float f) {
    unsigned int u = __float_as_uint(f);
    u += 0x7FFFu + ((u >> 16) & 1u);
    return (unsigned short)(u >> 16);
}
__device__ __forceinline__ unsigned int sub2bf(unsigned int a, unsigned int b) {
    float d0 = bf2f((unsigned short)(a & 0xFFFFu)) - bf2f((unsigned short)(b & 0xFFFFu));
    float d1 = bf2f((unsigned short)(a >> 16))     - bf2f((unsigned short)(b >> 16));
    return (unsigned int)f2bf(d0) | ((unsigned int)f2bf(d1) << 16);
}
// relu on two packed bf16 (zero the negative halves) — bit-exact vs fp32 relu.
__device__ __forceinline__ unsigned int relu2(unsigned int w) {
    unsigned int r = w;
    if (w & 0x80000000u) r &= 0x0000FFFFu;
    if (w & 0x00008000u) r &= 0xFFFF0000u;
    return r;
}
__device__ __forceinline__ uint4 relu4(uint4 v) {
    v.x = relu2(v.x); v.y = relu2(v.y); v.z = relu2(v.z); v.w = relu2(v.w);
    return v;
}
__device__ __forceinline__ uint4 subpack4(uint4 a, uint4 b) {
    uint4 r;
    r.x = sub2bf(a.x, b.x); r.y = sub2bf(a.y, b.y);
    r.z = sub2bf(a.z, b.z); r.w = sub2bf(a.w, b.w);
    return r;
}

// ---------------------------------------------------------------------------
// Fragment layout: element (m,k) at buf[((m_blk*S + s)*64 + lane)*8 + j],
// m = m_blk*32 + (lane&31), k = s*16 + (lane>>5)*8 + j. Same for B with n.

__global__ void __launch_bounds__(256)
pack_a_f32(const float* __restrict__ src, unsigned short* __restrict__ dst,
           int M, int K, int S, int MB)
{
    int g = blockIdx.x * 256 + threadIdx.x;
    int total = MB * S * 32;
    if (g >= total) return;
    int mrow = g & 31;
    int t = g >> 5;
    int s = t % S;
    int m_blk = t / S;
    int m = m_blk * 32 + mrow;
    unsigned int w[8];
#pragma unroll
    for (int q = 0; q < 2; ++q) {
#pragma unroll
        for (int p = 0; p < 4; ++p) {
            int k = s * 16 + q * 8 + p * 2;
            unsigned short h0 = (m < M && k     < K) ? f2bf(src[(size_t)m * K + k])     : (unsigned short)0;
            unsigned short h1 = (m < M && k + 1 < K) ? f2bf(src[(size_t)m * K + k + 1]) : (unsigned short)0;
            w[q * 4 + p] = (unsigned int)h0 | ((unsigned int)h1 << 16);
        }
    }
    size_t base = ((size_t)(m_blk * S + s) * 64) * 8;
    *(uint4*)&dst[base + (size_t)(0 * 32 + mrow) * 8] = make_uint4(w[0], w[1], w[2], w[3]);
    *(uint4*)&dst[base + (size_t)(1 * 32 + mrow) * 8] = make_uint4(w[4], w[5], w[6], w[7]);
}

__global__ void __launch_bounds__(256)
pack_b(const float* __restrict__ src1, const float* __restrict__ src2,
       unsigned short* __restrict__ dst, int K1, int S1, int K2, int SB)
{
    int g = blockIdx.x * 256 + threadIdx.x;
    if (g >= 10 * SB * 64) return;
    int lane = g & 63;
    int t = g >> 6;
    int s = t % SB;
    int n_blk = t / SB;
    int n = n_blk * 32 + (lane & 31);
    unsigned int w[4];
#pragma unroll
    for (int p = 0; p < 4; ++p) {
        unsigned short h[2];
#pragma unroll
        for (int e = 0; e < 2; ++e) {
            int kf = s * 16 + (lane >> 5) * 8 + p * 2 + e;
            float v = 0.0f;
            if (n < H) {
                if (s < S1) {
                    if (kf < K1) v = src1[(size_t)kf * H + n];
                } else {
                    int k2 = kf - S1 * 16;
                    if (k2 < K2) v = src2[(size_t)k2 * H + n];
                }
            }
            h[e] = f2bf(v);
        }
        w[p] = (unsigned int)h[0] | ((unsigned int)h[1] << 16);
    }
    *(uint4*)&dst[(size_t)g * 8] = make_uint4(w[0], w[1], w[2], w[3]);
}

// ---------------------------------------------------------------------------
// amsg[a][:] = sum_j maybe_relu(msg[a2b[a][j]][:]). One thread per 8 halfs.
template<int RELU>
__global__ void __launch_bounds__(256)
aggregate_row(const unsigned short* __restrict__ msg, const int* __restrict__ a2b,
              unsigned short* __restrict__ amsg, int n_atoms)
{
    int gid = blockIdx.x * 256 + threadIdx.x;
    int total = n_atoms * 38;
    if (gid >= total) return;
    int atom = gid / 38;
    int g8 = gid - atom * 38;
    const int* nb = a2b + atom * MAXNB;
    float sum[8] = {};
#pragma unroll
    for (int j = 0; j < MAXNB; ++j) {
        int b = nb[j];
        uint4 v = *(const uint4*)&msg[(size_t)b * RS + g8 * 8];
        if (RELU) v = relu4(v);
        unsigned int ww[4] = {v.x, v.y, v.z, v.w};
#pragma unroll
        for (int p = 0; p < 4; ++p) {
            sum[p * 2]     += bf2f((unsigned short)(ww[p] & 0xFFFFu));
            sum[p * 2 + 1] += bf2f((unsigned short)(ww[p] >> 16));
        }
    }
    unsigned int ow[4];
#pragma unroll
    for (int p = 0; p < 4; ++p)
        ow[p] = (unsigned int)f2bf(sum[p * 2]) | ((unsigned int)f2bf(sum[p * 2 + 1]) << 16);
    *(uint4*)&amsg[(size_t)atom * RS + g8 * 8] = make_uint4(ow[0], ow[1], ow[2], ow[3]);
}

// ---------------------------------------------------------------------------
// Fused MFMA GEMM, distance-2 B prefetch, row-per-thread gather staging.
// MODE 0 (init): A = A1 packed. out = raw A@B (no activation).
// MODE 1 (mp):   A = LDS-staged (amsg[b2a[m]] - maybe_relu(msg[b2revb[m]])).
//                out = relu(A@B + inp_add).
// MODE 2 (cat):  A = [A1 packed | LDS-staged amsg rows]. out = relu(A@B + bias).
template<int S1, int S2, int SBL, int MODE, int RELUMSG>
__global__ void __launch_bounds__(256, 4)
gemm_fused(const unsigned short* __restrict__ A1,
           const unsigned short* __restrict__ amsg,
           const unsigned short* __restrict__ msg,
           const int* __restrict__ b2a, const int* __restrict__ b2revb,
           const unsigned short* __restrict__ Bp,
           const float* __restrict__ bias,
           const unsigned short* __restrict__ inp_add,
           unsigned short* __restrict__ out, int M)
{
    __shared__ __align__(16) unsigned short smem[64 * ASTR]; // Ast / Cs union

    const int lane  = threadIdx.x & 63;
    const int w     = threadIdx.x >> 6;
    const int rbase = (w >> 1) * 32;
    const int cbase = (w & 1) * 160;
    const int mrow  = lane & 31;
    const int quad  = lane >> 5;
    const int m0    = blockIdx.x * 64;
    const int m_blk = blockIdx.x * 2 + (w >> 1);
    const int nblk0 = cbase >> 5;

    // ---- Stage gathered A-tile: thread t owns row t>>2, chunk set (t&3)+4i.
    if (MODE == 1 || MODE == 2) {
        const int r = threadIdx.x >> 2;
        const int q = threadIdx.x & 3;
        int mm = m0 + r;
        int mv = (mm < M) ? mm : 0;
        const unsigned short* rowA;
        const unsigned short* rowM = nullptr;
        if (MODE == 1) {
            rowA = amsg + (size_t)b2a[mv] * RS;
            rowM = msg  + (size_t)b2revb[mv] * RS;
        } else {
            rowA = amsg + (size_t)mv * RS;
        }
#pragma unroll
        for (int i = 0; i < 10; ++i) {
            int c = q + i * 4;
            if (c < 38) {
                uint4 o;
                if (MODE == 1) {
                    uint4 va = *(const uint4*)(rowA + c * 8);
                    uint4 vm = *(const uint4*)(rowM + c * 8);
                    if (RELUMSG) vm = relu4(vm);
                    o = subpack4(va, vm);
                } else {
                    o = *(const uint4*)(rowA + c * 8);
                }
                *(uint4*)&smem[r * ASTR + c * 8] = o;
            }
        }
        __syncthreads();
    }

    f32x16 acc[5];
#pragma unroll
    for (int t = 0; t < 5; ++t)
#pragma unroll
        for (int i = 0; i < 16; ++i) acc[t][i] = 0.0f;

    const unsigned short* pa1 = (S1 > 0) ? (A1 + ((size_t)m_blk * S1 * 64 + lane) * 8) : nullptr;
    const unsigned short* pb  = Bp + ((size_t)nblk0 * SBL * 64 + lane) * 8;

    constexpr int STOT = S1 + S2;

    auto loadA = [&](int s) -> bf16x8 {
        if (s < S1) return *(const bf16x8*)(pa1 + (size_t)s * 512);
        return *(const bf16x8*)&smem[(rbase + mrow) * ASTR + (s - S1) * 16 + quad * 8];
    };

    bf16x8 b0[5], b1[5];
#pragma unroll
    for (int nt = 0; nt < 5; ++nt) b0[nt] = *(const bf16x8*)(pb + ((size_t)nt * SBL + 0) * 512);
    if (STOT > 1) {
#pragma unroll
        for (int nt = 0; nt < 5; ++nt) b1[nt] = *(const bf16x8*)(pb + ((size_t)nt * SBL + 1) * 512);
    }

#pragma unroll
    for (int s = 0; s < STOT; s += 2) {
        bf16x8 a = loadA(s);
        acc[0] = __builtin_amdgcn_mfma_f32_32x32x16_bf16(a, b0[0], acc[0], 0, 0, 0);
        acc[1] = __builtin_amdgcn_mfma_f32_32x32x16_bf16(a, b0[1], acc[1], 0, 0, 0);
        acc[2] = __builtin_amdgcn_mfma_f32_32x32x16_bf16(a, b0[2], acc[2], 0, 0, 0);
        acc[3] = __builtin_amdgcn_mfma_f32_32x32x16_bf16(a, b0[3], acc[3], 0, 0, 0);
        acc[4] = __builtin_amdgcn_mfma_f32_32x32x16_bf16(a, b0[4], acc[4], 0, 0, 0);
        if (s + 2 < STOT) {
#pragma unroll
            for (int nt = 0; nt < 5; ++nt) b0[nt] = *(const bf16x8*)(pb + ((size_t)nt * SBL + s + 2) * 512);
        }
        if (s + 1 < STOT) {
            bf16x8 a2 = loadA(s + 1);
            acc[0] = __builtin_amdgcn_mfma_f32_32x32x16_bf16(a2, b1[0], acc[0], 0, 0, 0);
            acc[1] = __builtin_amdgcn_mfma_f32_32x32x16_bf16(a2, b1[1], acc[1], 0, 0, 0);
            acc[2] = __builtin_amdgcn_mfma_f32_32x32x16_bf16(a2, b1[2], acc[2], 0, 0, 0);
            acc[3] = __builtin_amdgcn_mfma_f32_32x32x16_bf16(a2, b1[3], acc[3], 0, 0, 0);
            acc[4] = __builtin_amdgcn_mfma_f32_32x32x16_bf16(a2, b1[4], acc[4], 0, 0, 0);
            if (s + 3 < STOT) {
#pragma unroll
                for (int nt = 0; nt < 5; ++nt) b1[nt] = *(const bf16x8*)(pb + ((size_t)nt * SBL + s + 3) * 512);
            }
        }
    }

    __syncthreads();   // Ast reads done before Cs overwrites the union

    // C/D: col = lane&31 (+tile), row = (reg&3)+8*(reg>>2)+4*quad (+rbase). Raw.
#pragma unroll
    for (int nt = 0; nt < 5; ++nt) {
        int col = cbase + nt * 32 + mrow;
#pragma unroll
        for (int r = 0; r < 16; ++r) {
            int row = rbase + (r & 3) + 8 * (r >> 2) + 4 * quad;
            if (col < 308) smem[row * 308 + col] = f2bf(acc[nt][r]);
        }
    }
    __syncthreads();

    // Coalesced copy-out with fused epilogue math.
    for (int idx = threadIdx.x; idx < 64 * 76; idx += 256) {
        int row = idx / 76, gcol = idx - row * 76;
        int mm = m0 + row;
        if (mm >= M) continue;
        int c0 = gcol * 4;
        uint2 raw = *(const uint2*)&smem[row * 308 + c0];
        uint2 o;
        if (MODE == 0) {
            o = raw;   // raw pre-activation store (relu applied at consumers)
        } else {
            unsigned short h[4] = {(unsigned short)(raw.x & 0xFFFFu), (unsigned short)(raw.x >> 16),
                                   (unsigned short)(raw.y & 0xFFFFu), (unsigned short)(raw.y >> 16)};
            float v[4];
#pragma unroll
            for (int e = 0; e < 4; ++e) v[e] = bf2f(h[e]);
            if (MODE == 1) {
                uint2 iv = *(const uint2*)&inp_add[(size_t)mm * RS + c0];
                v[0] += bf2f((unsigned short)(iv.x & 0xFFFFu));
                v[1] += bf2f((unsigned short)(iv.x >> 16));
                v[2] += bf2f((unsigned short)(iv.y & 0xFFFFu));
                v[3] += bf2f((unsigned short)(iv.y >> 16));
            } else {
#pragma unroll
                for (int e = 0; e < 4; ++e) v[e] += (c0 + e < H) ? bias[c0 + e] : 0.0f;
            }
#pragma unroll
            for (int e = 0; e < 4; ++e) h[e] = f2bf(fmaxf(v[e], 0.0f));
            o.x = (unsigned int)h[0] | ((unsigned int)h[1] << 16);
            o.y = (unsigned int)h[2] | ((unsigned int)h[3] << 16);
        }
        *(uint2*)&out[(size_t)mm * RS + c0] = o;
    }
}

// ---------------------------------------------------------------------------
__global__ void __launch_bounds__(128)
segmean_kernel(const unsigned short* __restrict__ ah,
               const int* __restrict__ mol_id, int n_atoms,
               float* __restrict__ out)
{
    int m = blockIdx.x;
    int lo = 0, hi = n_atoms;
    while (lo < hi) { int mid = (lo + hi) >> 1; if (mol_id[mid] < m) lo = mid + 1; else hi = mid; }
    int start = lo;
    hi = n_atoms;
    while (lo < hi) { int mid = (lo + hi) >> 1; if (mol_id[mid] < m + 1) lo = mid + 1; else hi = mid; }
    int end = lo;

    int c = threadIdx.x;
    float a0 = 0.f, a1 = 0.f, a2 = 0.f;
    for (int a = start; a < end; ++a) {
        const unsigned short* row = ah + (size_t)a * RS;
        a0 += bf2f(row[c]);
        a1 += bf2f(row[c + 128]);
        if (c < H - 256) a2 += bf2f(row[c + 256]);
    }
    float inv = (end > start) ? 1.0f / (float)(end - start) : 0.0f;
    float* orow = out + (size_t)m * H;
    orow[c] = a0 * inv;
    orow[c + 128] = a1 * inv;
    if (c < H - 256) orow[c + 256] = a2 * inv;
}

// ---------------------------------------------------------------------------
extern "C" void kernel_launch(void* const* d_in, const int* in_sizes, int n_in,
                              void* d_out, int out_size, void* d_ws, size_t ws_size,
                              hipStream_t stream)
{
    const float* f_atoms = (const float*)d_in[0];
    const float* f_bonds = (const float*)d_in[1];
    const int*   a2b     = (const int*)d_in[2];
    const int*   b2a     = (const int*)d_in[3];
    const int*   b2revb  = (const int*)d_in[4];
    const int*   mol_id  = (const int*)d_in[5];
    const float* W_i     = (const float*)d_in[7];
    const float* W_h     = (const float*)d_in[8];
    const float* W_o     = (const float*)d_in[9];
    const float* b_o     = (const float*)d_in[10];

    const int n_atoms   = in_sizes[5];
    const int n_bonds   = in_sizes[3];
    const int atom_fdim = in_sizes[0] / n_atoms;   // 133
    const int bond_fdim = in_sizes[1] / n_bonds;   // 147
    const int n_mols    = out_size / H;            // 2000

    const int gBonds = (n_bonds + 63) / 64;
    const int gAtoms = (n_atoms + 63) / 64;
    const int MBb = 2 * gBonds;
    const int MBa = 2 * gAtoms;

    const size_t bondsRS = (size_t)n_bonds * RS;
    const size_t atomsRS = (size_t)n_atoms * RS;
    const size_t fbpSz   = (size_t)MBb * 10 * 512;
    const size_t wihSz   = 10 * 30 * 512;
    const size_t woSz    = 10 * 29 * 512;
    const size_t wh19Sz  = 10 * 19 * 512;

    // Layout (halfs): inp | msgB | amsg | fbp | wih | wo | wh19
    // Overlays: iter-2 mp writes message2 in-place over inp (audited safe);
    //           fap overlays inp after final aggregate; ah overlays fbp.
    unsigned short* inp  = (unsigned short*)d_ws;
    unsigned short* msgB = inp  + bondsRS;
    unsigned short* amsg = msgB + bondsRS;
    unsigned short* fbp  = amsg + atomsRS;
    unsigned short* wih  = fbp  + fbpSz;
    unsigned short* wo   = wih  + wihSz;
    unsigned short* wh19 = wo   + woSz;
    unsigned short* fap  = inp;
    unsigned short* ah   = fbp;

    dim3 blk(256);
    const int aggBlocks = (n_atoms * 38 + 255) / 256;

    pack_b<<<(10 * 30 * 64 + 255) / 256, blk, 0, stream>>>(W_i, W_h, wih, bond_fdim, 10, H, 30);
    pack_b<<<(10 * 19 * 64 + 255) / 256, blk, 0, stream>>>(W_h, W_h, wh19, H, 19, 0, 19);
    pack_b<<<(10 * 29 * 64 + 255) / 256, blk, 0, stream>>>(W_o, W_o + (size_t)atom_fdim * H, wo,
                                                           atom_fdim, 9, H, 29);
    pack_a_f32<<<(MBb * 10 * 32 + 255) / 256, blk, 0, stream>>>(f_bonds, fbp, n_bonds, bond_fdim, 10, MBb);

    // init: inp = f_bonds @ W_i  (raw; consumers apply relu)
    gemm_fused<10, 0, 30, 0, 0><<<gBonds, blk, 0, stream>>>(
        fbp, nullptr, nullptr, nullptr, nullptr, wih, nullptr, nullptr, inp, n_bonds);

    // iter 1: message1 = relu(inp + (amsg[b2a] - relu(inp[b2revb])) @ W_h) -> msgB
    aggregate_row<1><<<aggBlocks, blk, 0, stream>>>(inp, a2b, amsg, n_atoms);
    gemm_fused<0, 19, 19, 1, 1><<<gBonds, blk, 0, stream>>>(
        nullptr, amsg, inp, b2a, b2revb, wh19, nullptr, inp, msgB, n_bonds);

    // iter 2: message2 -> inp (in-place; inp only read by this kernel's epilogue)
    aggregate_row<0><<<aggBlocks, blk, 0, stream>>>(msgB, a2b, amsg, n_atoms);
    gemm_fused<0, 19, 19, 1, 0><<<gBonds, blk, 0, stream>>>(
        nullptr, amsg, msgB, b2a, b2revb, wh19, nullptr, inp, inp, n_bonds);

    // final aggregation from message2
    aggregate_row<0><<<aggBlocks, blk, 0, stream>>>(inp, a2b, amsg, n_atoms);

    // f_atoms pack (overlays inp region — dead after final aggregate)
    pack_a_f32<<<(MBa * 9 * 32 + 255) / 256, blk, 0, stream>>>(f_atoms, fap, n_atoms, atom_fdim, 9, MBa);

    // cat GEMM: ah = relu([f_atoms | amsg] @ W_o + b_o)
    gemm_fused<9, 19, 29, 2, 0><<<gAtoms, blk, 0, stream>>>(
        fap, amsg, nullptr, nullptr, nullptr, wo, b_o, nullptr, ah, n_atoms);

    segmean_kernel<<<n_mols, dim3(128), 0, stream>>>(ah, mol_id, n_atoms, (float*)d_out);
}

// Round 11
// 543.195 us; speedup vs baseline: 1.8717x; 1.8717x over previous
//
#include <hip/hip_runtime.h>
#include <cstddef>

#define H 300
#define RS 304            // row stride (halfs) for row-major bf16 buffers
#define MAXNB 6
#define ASTR 312          // LDS A-tile stride (halfs)

typedef __attribute__((ext_vector_type(8)))  short bf16x8;
typedef __attribute__((ext_vector_type(16))) float f32x16;

__device__ __forceinline__ float bf2f(unsigned short u) {
    return __uint_as_float(((unsigned int)u) << 16);
}
__device__ __forceinline__ unsigned short f2bf(float f) {
    unsigned int u = __float_as_uint(f);
    u += 0x7FFFu + ((u >> 16) & 1u);
    return (unsigned short)(u >> 16);
}
__device__ __forceinline__ unsigned int sub2bf(unsigned int a, unsigned int b) {
    float d0 = bf2f((unsigned short)(a & 0xFFFFu)) - bf2f((unsigned short)(b & 0xFFFFu));
    float d1 = bf2f((unsigned short)(a >> 16))     - bf2f((unsigned short)(b >> 16));
    return (unsigned int)f2bf(d0) | ((unsigned int)f2bf(d1) << 16);
}
// relu on two packed bf16 (zero the negative halves) — bit-exact vs fp32 relu.
__device__ __forceinline__ unsigned int relu2(unsigned int w) {
    unsigned int r = w;
    if (w & 0x80000000u) r &= 0x0000FFFFu;
    if (w & 0x00008000u) r &= 0xFFFF0000u;
    return r;
}
__device__ __forceinline__ uint4 relu4(uint4 v) {
    v.x = relu2(v.x); v.y = relu2(v.y); v.z = relu2(v.z); v.w = relu2(v.w);
    return v;
}
__device__ __forceinline__ uint4 subpack4(uint4 a, uint4 b) {
    uint4 r;
    r.x = sub2bf(a.x, b.x); r.y = sub2bf(a.y, b.y);
    r.z = sub2bf(a.z, b.z); r.w = sub2bf(a.w, b.w);
    return r;
}

// ---------------------------------------------------------------------------
// Fragment layout: element (m,k) at buf[((m_blk*S + s)*64 + lane)*8 + j],
// m = m_blk*32 + (lane&31), k = s*16 + (lane>>5)*8 + j. Same for B with n.

__global__ void __launch_bounds__(256)
pack_a_f32(const float* __restrict__ src, unsigned short* __restrict__ dst,
           int M, int K, int S, int MB)
{
    int g = blockIdx.x * 256 + threadIdx.x;
    int total = MB * S * 32;
    if (g >= total) return;
    int mrow = g & 31;
    int t = g >> 5;
    int s = t % S;
    int m_blk = t / S;
    int m = m_blk * 32 + mrow;
    unsigned int w[8];
#pragma unroll
    for (int q = 0; q < 2; ++q) {
#pragma unroll
        for (int p = 0; p < 4; ++p) {
            int k = s * 16 + q * 8 + p * 2;
            unsigned short h0 = (m < M && k     < K) ? f2bf(src[(size_t)m * K + k])     : (unsigned short)0;
            unsigned short h1 = (m < M && k + 1 < K) ? f2bf(src[(size_t)m * K + k + 1]) : (unsigned short)0;
            w[q * 4 + p] = (unsigned int)h0 | ((unsigned int)h1 << 16);
        }
    }
    size_t base = ((size_t)(m_blk * S + s) * 64) * 8;
    *(uint4*)&dst[base + (size_t)(0 * 32 + mrow) * 8] = make_uint4(w[0], w[1], w[2], w[3]);
    *(uint4*)&dst[base + (size_t)(1 * 32 + mrow) * 8] = make_uint4(w[4], w[5], w[6], w[7]);
}

__global__ void __launch_bounds__(256)
pack_b(const float* __restrict__ src1, const float* __restrict__ src2,
       unsigned short* __restrict__ dst, int K1, int S1, int K2, int SB)
{
    int g = blockIdx.x * 256 + threadIdx.x;
    if (g >= 10 * SB * 64) return;
    int lane = g & 63;
    int t = g >> 6;
    int s = t % SB;
    int n_blk = t / SB;
    int n = n_blk * 32 + (lane & 31);
    unsigned int w[4];
#pragma unroll
    for (int p = 0; p < 4; ++p) {
        unsigned short h[2];
#pragma unroll
        for (int e = 0; e < 2; ++e) {
            int kf = s * 16 + (lane >> 5) * 8 + p * 2 + e;
            float v = 0.0f;
            if (n < H) {
                if (s < S1) {
                    if (kf < K1) v = src1[(size_t)kf * H + n];
                } else {
                    int k2 = kf - S1 * 16;
                    if (k2 < K2) v = src2[(size_t)k2 * H + n];
                }
            }
            h[e] = f2bf(v);
        }
        w[p] = (unsigned int)h[0] | ((unsigned int)h[1] << 16);
    }
    *(uint4*)&dst[(size_t)g * 8] = make_uint4(w[0], w[1], w[2], w[3]);
}

// ---------------------------------------------------------------------------
// amsg[a][:] = sum_j maybe_relu(msg[a2b[a][j]][:]). One thread per 8 halfs.
template<int RELU>
__global__ void __launch_bounds__(256)
aggregate_row(const unsigned short* __restrict__ msg, const int* __restrict__ a2b,
              unsigned short* __restrict__ amsg, int n_atoms)
{
    int gid = blockIdx.x * 256 + threadIdx.x;
    int total = n_atoms * 38;
    if (gid >= total) return;
    int atom = gid / 38;
    int g8 = gid - atom * 38;
    const int* nb = a2b + atom * MAXNB;
    float sum[8] = {};
#pragma unroll
    for (int j = 0; j < MAXNB; ++j) {
        int b = nb[j];
        uint4 v = *(const uint4*)&msg[(size_t)b * RS + g8 * 8];
        if (RELU) v = relu4(v);
        unsigned int ww[4] = {v.x, v.y, v.z, v.w};
#pragma unroll
        for (int p = 0; p < 4; ++p) {
            sum[p * 2]     += bf2f((unsigned short)(ww[p] & 0xFFFFu));
            sum[p * 2 + 1] += bf2f((unsigned short)(ww[p] >> 16));
        }
    }
    unsigned int ow[4];
#pragma unroll
    for (int p = 0; p < 4; ++p)
        ow[p] = (unsigned int)f2bf(sum[p * 2]) | ((unsigned int)f2bf(sum[p * 2 + 1]) << 16);
    *(uint4*)&amsg[(size_t)atom * RS + g8 * 8] = make_uint4(ow[0], ow[1], ow[2], ow[3]);
}

// ---------------------------------------------------------------------------
// Fused MFMA GEMM, distance-2 B prefetch, row-per-thread gather staging.
// NOTE: no waves-per-EU cap — acc[5] needs 80 AGPRs + 40 VGPR prefetch regs;
// capping at 4 waves/EU (R10) forced accumulator spills (WRITE_SIZE 530 MB).
// MODE 0 (init): A = A1 packed. out = raw A@B (no activation).
// MODE 1 (mp):   A = LDS-staged (amsg[b2a[m]] - maybe_relu(msg[b2revb[m]])).
//                out = relu(A@B + inp_add).
// MODE 2 (cat):  A = [A1 packed | LDS-staged amsg rows]. out = relu(A@B + bias).
template<int S1, int S2, int SBL, int MODE, int RELUMSG>
__global__ void __launch_bounds__(256)
gemm_fused(const unsigned short* __restrict__ A1,
           const unsigned short* __restrict__ amsg,
           const unsigned short* __restrict__ msg,
           const int* __restrict__ b2a, const int* __restrict__ b2revb,
           const unsigned short* __restrict__ Bp,
           const float* __restrict__ bias,
           const unsigned short* __restrict__ inp_add,
           unsigned short* __restrict__ out, int M)
{
    __shared__ __align__(16) unsigned short smem[64 * ASTR]; // Ast / Cs union

    const int lane  = threadIdx.x & 63;
    const int w     = threadIdx.x >> 6;
    const int rbase = (w >> 1) * 32;
    const int cbase = (w & 1) * 160;
    const int mrow  = lane & 31;
    const int quad  = lane >> 5;
    const int m0    = blockIdx.x * 64;
    const int m_blk = blockIdx.x * 2 + (w >> 1);
    const int nblk0 = cbase >> 5;

    // ---- Stage gathered A-tile: thread t owns row t>>2, chunk set (t&3)+4i.
    if (MODE == 1 || MODE == 2) {
        const int r = threadIdx.x >> 2;
        const int q = threadIdx.x & 3;
        int mm = m0 + r;
        int mv = (mm < M) ? mm : 0;
        const unsigned short* rowA;
        const unsigned short* rowM = nullptr;
        if (MODE == 1) {
            rowA = amsg + (size_t)b2a[mv] * RS;
            rowM = msg  + (size_t)b2revb[mv] * RS;
        } else {
            rowA = amsg + (size_t)mv * RS;
        }
#pragma unroll
        for (int i = 0; i < 10; ++i) {
            int c = q + i * 4;
            if (c < 38) {
                uint4 o;
                if (MODE == 1) {
                    uint4 va = *(const uint4*)(rowA + c * 8);
                    uint4 vm = *(const uint4*)(rowM + c * 8);
                    if (RELUMSG) vm = relu4(vm);
                    o = subpack4(va, vm);
                } else {
                    o = *(const uint4*)(rowA + c * 8);
                }
                *(uint4*)&smem[r * ASTR + c * 8] = o;
            }
        }
        __syncthreads();
    }

    f32x16 acc[5];
#pragma unroll
    for (int t = 0; t < 5; ++t)
#pragma unroll
        for (int i = 0; i < 16; ++i) acc[t][i] = 0.0f;

    const unsigned short* pa1 = (S1 > 0) ? (A1 + ((size_t)m_blk * S1 * 64 + lane) * 8) : nullptr;
    const unsigned short* pb  = Bp + ((size_t)nblk0 * SBL * 64 + lane) * 8;

    constexpr int STOT = S1 + S2;

    auto loadA = [&](int s) -> bf16x8 {
        if (s < S1) return *(const bf16x8*)(pa1 + (size_t)s * 512);
        return *(const bf16x8*)&smem[(rbase + mrow) * ASTR + (s - S1) * 16 + quad * 8];
    };

    bf16x8 b0[5], b1[5];
#pragma unroll
    for (int nt = 0; nt < 5; ++nt) b0[nt] = *(const bf16x8*)(pb + ((size_t)nt * SBL + 0) * 512);
    if (STOT > 1) {
#pragma unroll
        for (int nt = 0; nt < 5; ++nt) b1[nt] = *(const bf16x8*)(pb + ((size_t)nt * SBL + 1) * 512);
    }

#pragma unroll
    for (int s = 0; s < STOT; s += 2) {
        bf16x8 a = loadA(s);
        acc[0] = __builtin_amdgcn_mfma_f32_32x32x16_bf16(a, b0[0], acc[0], 0, 0, 0);
        acc[1] = __builtin_amdgcn_mfma_f32_32x32x16_bf16(a, b0[1], acc[1], 0, 0, 0);
        acc[2] = __builtin_amdgcn_mfma_f32_32x32x16_bf16(a, b0[2], acc[2], 0, 0, 0);
        acc[3] = __builtin_amdgcn_mfma_f32_32x32x16_bf16(a, b0[3], acc[3], 0, 0, 0);
        acc[4] = __builtin_amdgcn_mfma_f32_32x32x16_bf16(a, b0[4], acc[4], 0, 0, 0);
        if (s + 2 < STOT) {
#pragma unroll
            for (int nt = 0; nt < 5; ++nt) b0[nt] = *(const bf16x8*)(pb + ((size_t)nt * SBL + s + 2) * 512);
        }
        if (s + 1 < STOT) {
            bf16x8 a2 = loadA(s + 1);
            acc[0] = __builtin_amdgcn_mfma_f32_32x32x16_bf16(a2, b1[0], acc[0], 0, 0, 0);
            acc[1] = __builtin_amdgcn_mfma_f32_32x32x16_bf16(a2, b1[1], acc[1], 0, 0, 0);
            acc[2] = __builtin_amdgcn_mfma_f32_32x32x16_bf16(a2, b1[2], acc[2], 0, 0, 0);
            acc[3] = __builtin_amdgcn_mfma_f32_32x32x16_bf16(a2, b1[3], acc[3], 0, 0, 0);
            acc[4] = __builtin_amdgcn_mfma_f32_32x32x16_bf16(a2, b1[4], acc[4], 0, 0, 0);
            if (s + 3 < STOT) {
#pragma unroll
                for (int nt = 0; nt < 5; ++nt) b1[nt] = *(const bf16x8*)(pb + ((size_t)nt * SBL + s + 3) * 512);
            }
        }
    }

    __syncthreads();   // Ast reads done before Cs overwrites the union

    // C/D: col = lane&31 (+tile), row = (reg&3)+8*(reg>>2)+4*quad (+rbase). Raw.
#pragma unroll
    for (int nt = 0; nt < 5; ++nt) {
        int col = cbase + nt * 32 + mrow;
#pragma unroll
        for (int r = 0; r < 16; ++r) {
            int row = rbase + (r & 3) + 8 * (r >> 2) + 4 * quad;
            if (col < 308) smem[row * 308 + col] = f2bf(acc[nt][r]);
        }
    }
    __syncthreads();

    // Coalesced copy-out with fused epilogue math.
    for (int idx = threadIdx.x; idx < 64 * 76; idx += 256) {
        int row = idx / 76, gcol = idx - row * 76;
        int mm = m0 + row;
        if (mm >= M) continue;
        int c0 = gcol * 4;
        uint2 raw = *(const uint2*)&smem[row * 308 + c0];
        uint2 o;
        if (MODE == 0) {
            o = raw;   // raw pre-activation store (relu applied at consumers)
        } else {
            unsigned short h[4] = {(unsigned short)(raw.x & 0xFFFFu), (unsigned short)(raw.x >> 16),
                                   (unsigned short)(raw.y & 0xFFFFu), (unsigned short)(raw.y >> 16)};
            float v[4];
#pragma unroll
            for (int e = 0; e < 4; ++e) v[e] = bf2f(h[e]);
            if (MODE == 1) {
                uint2 iv = *(const uint2*)&inp_add[(size_t)mm * RS + c0];
                v[0] += bf2f((unsigned short)(iv.x & 0xFFFFu));
                v[1] += bf2f((unsigned short)(iv.x >> 16));
                v[2] += bf2f((unsigned short)(iv.y & 0xFFFFu));
                v[3] += bf2f((unsigned short)(iv.y >> 16));
            } else {
#pragma unroll
                for (int e = 0; e < 4; ++e) v[e] += (c0 + e < H) ? bias[c0 + e] : 0.0f;
            }
#pragma unroll
            for (int e = 0; e < 4; ++e) h[e] = f2bf(fmaxf(v[e], 0.0f));
            o.x = (unsigned int)h[0] | ((unsigned int)h[1] << 16);
            o.y = (unsigned int)h[2] | ((unsigned int)h[3] << 16);
        }
        *(uint2*)&out[(size_t)mm * RS + c0] = o;
    }
}

// ---------------------------------------------------------------------------
__global__ void __launch_bounds__(128)
segmean_kernel(const unsigned short* __restrict__ ah,
               const int* __restrict__ mol_id, int n_atoms,
               float* __restrict__ out)
{
    int m = blockIdx.x;
    int lo = 0, hi = n_atoms;
    while (lo < hi) { int mid = (lo + hi) >> 1; if (mol_id[mid] < m) lo = mid + 1; else hi = mid; }
    int start = lo;
    hi = n_atoms;
    while (lo < hi) { int mid = (lo + hi) >> 1; if (mol_id[mid] < m + 1) lo = mid + 1; else hi = mid; }
    int end = lo;

    int c = threadIdx.x;
    float a0 = 0.f, a1 = 0.f, a2 = 0.f;
    for (int a = start; a < end; ++a) {
        const unsigned short* row = ah + (size_t)a * RS;
        a0 += bf2f(row[c]);
        a1 += bf2f(row[c + 128]);
        if (c < H - 256) a2 += bf2f(row[c + 256]);
    }
    float inv = (end > start) ? 1.0f / (float)(end - start) : 0.0f;
    float* orow = out + (size_t)m * H;
    orow[c] = a0 * inv;
    orow[c + 128] = a1 * inv;
    if (c < H - 256) orow[c + 256] = a2 * inv;
}

// ---------------------------------------------------------------------------
extern "C" void kernel_launch(void* const* d_in, const int* in_sizes, int n_in,
                              void* d_out, int out_size, void* d_ws, size_t ws_size,
                              hipStream_t stream)
{
    const float* f_atoms = (const float*)d_in[0];
    const float* f_bonds = (const float*)d_in[1];
    const int*   a2b     = (const int*)d_in[2];
    const int*   b2a     = (const int*)d_in[3];
    const int*   b2revb  = (const int*)d_in[4];
    const int*   mol_id  = (const int*)d_in[5];
    const float* W_i     = (const float*)d_in[7];
    const float* W_h     = (const float*)d_in[8];
    const float* W_o     = (const float*)d_in[9];
    const float* b_o     = (const float*)d_in[10];

    const int n_atoms   = in_sizes[5];
    const int n_bonds   = in_sizes[3];
    const int atom_fdim = in_sizes[0] / n_atoms;   // 133
    const int bond_fdim = in_sizes[1] / n_bonds;   // 147
    const int n_mols    = out_size / H;            // 2000

    const int gBonds = (n_bonds + 63) / 64;
    const int gAtoms = (n_atoms + 63) / 64;
    const int MBb = 2 * gBonds;
    const int MBa = 2 * gAtoms;

    const size_t bondsRS = (size_t)n_bonds * RS;
    const size_t atomsRS = (size_t)n_atoms * RS;
    const size_t fbpSz   = (size_t)MBb * 10 * 512;
    const size_t wihSz   = 10 * 30 * 512;
    const size_t woSz    = 10 * 29 * 512;
    const size_t wh19Sz  = 10 * 19 * 512;

    // Layout (halfs): inp | msgB | amsg | fbp | wih | wo | wh19
    // Overlays: iter-2 mp writes message2 in-place over inp (audited safe);
    //           fap overlays inp after final aggregate; ah overlays fbp.
    unsigned short* inp  = (unsigned short*)d_ws;
    unsigned short* msgB = inp  + bondsRS;
    unsigned short* amsg = msgB + bondsRS;
    unsigned short* fbp  = amsg + atomsRS;
    unsigned short* wih  = fbp  + fbpSz;
    unsigned short* wo   = wih  + wihSz;
    unsigned short* wh19 = wo   + woSz;
    unsigned short* fap  = inp;
    unsigned short* ah   = fbp;

    dim3 blk(256);
    const int aggBlocks = (n_atoms * 38 + 255) / 256;

    pack_b<<<(10 * 30 * 64 + 255) / 256, blk, 0, stream>>>(W_i, W_h, wih, bond_fdim, 10, H, 30);
    pack_b<<<(10 * 19 * 64 + 255) / 256, blk, 0, stream>>>(W_h, W_h, wh19, H, 19, 0, 19);
    pack_b<<<(10 * 29 * 64 + 255) / 256, blk, 0, stream>>>(W_o, W_o + (size_t)atom_fdim * H, wo,
                                                           atom_fdim, 9, H, 29);
    pack_a_f32<<<(MBb * 10 * 32 + 255) / 256, blk, 0, stream>>>(f_bonds, fbp, n_bonds, bond_fdim, 10, MBb);

    // init: inp = f_bonds @ W_i  (raw; consumers apply relu)
    gemm_fused<10, 0, 30, 0, 0><<<gBonds, blk, 0, stream>>>(
        fbp, nullptr, nullptr, nullptr, nullptr, wih, nullptr, nullptr, inp, n_bonds);

    // iter 1: message1 = relu(inp + (amsg[b2a] - relu(inp[b2revb])) @ W_h) -> msgB
    aggregate_row<1><<<aggBlocks, blk, 0, stream>>>(inp, a2b, amsg, n_atoms);
    gemm_fused<0, 19, 19, 1, 1><<<gBonds, blk, 0, stream>>>(
        nullptr, amsg, inp, b2a, b2revb, wh19, nullptr, inp, msgB, n_bonds);

    // iter 2: message2 -> inp (in-place; inp only read by this kernel's epilogue)
    aggregate_row<0><<<aggBlocks, blk, 0, stream>>>(msgB, a2b, amsg, n_atoms);
    gemm_fused<0, 19, 19, 1, 0><<<gBonds, blk, 0, stream>>>(
        nullptr, amsg, msgB, b2a, b2revb, wh19, nullptr, inp, inp, n_bonds);

    // final aggregation from message2
    aggregate_row<0><<<aggBlocks, blk, 0, stream>>>(inp, a2b, amsg, n_atoms);

    // f_atoms pack (overlays inp region — dead after final aggregate)
    pack_a_f32<<<(MBa * 9 * 32 + 255) / 256, blk, 0, stream>>>(f_atoms, fap, n_atoms, atom_fdim, 9, MBa);

    // cat GEMM: ah = relu([f_atoms | amsg] @ W_o + b_o)
    gemm_fused<9, 19, 29, 2, 0><<<gAtoms, blk, 0, stream>>>(
        fap, amsg, nullptr, nullptr, nullptr, wo, b_o, nullptr, ah, n_atoms);

    segmean_kernel<<<n_mols, dim3(128), 0, stream>>>(ah, mol_id, n_atoms, (float*)d_out);
}

// Round 12
// 516.614 us; speedup vs baseline: 1.9680x; 1.0515x over previous
//
#include <hip/hip_runtime.h>
#include <cstddef>

#define H 300
#define RS 304            // row stride (halfs) for row-major bf16 buffers
#define MAXNB 6
#define ASTR 312          // LDS A-tile stride (halfs); 624 B rows, 16B-divisible

typedef __attribute__((ext_vector_type(8)))  short bf16x8;
typedef __attribute__((ext_vector_type(16))) float f32x16;

__device__ __forceinline__ float bf2f(unsigned short u) {
    return __uint_as_float(((unsigned int)u) << 16);
}
__device__ __forceinline__ unsigned short f2bf(float f) {
    unsigned int u = __float_as_uint(f);
    u += 0x7FFFu + ((u >> 16) & 1u);
    return (unsigned short)(u >> 16);
}
__device__ __forceinline__ unsigned int sub2bf(unsigned int a, unsigned int b) {
    float d0 = bf2f((unsigned short)(a & 0xFFFFu)) - bf2f((unsigned short)(b & 0xFFFFu));
    float d1 = bf2f((unsigned short)(a >> 16))     - bf2f((unsigned short)(b >> 16));
    return (unsigned int)f2bf(d0) | ((unsigned int)f2bf(d1) << 16);
}
// relu on two packed bf16 (zero the negative halves) — bit-exact vs fp32 relu.
__device__ __forceinline__ unsigned int relu2(unsigned int w) {
    unsigned int r = w;
    if (w & 0x80000000u) r &= 0x0000FFFFu;
    if (w & 0x00008000u) r &= 0xFFFF0000u;
    return r;
}
__device__ __forceinline__ uint4 relu4(uint4 v) {
    v.x = relu2(v.x); v.y = relu2(v.y); v.z = relu2(v.z); v.w = relu2(v.w);
    return v;
}
__device__ __forceinline__ uint4 subpack4(uint4 a, uint4 b) {
    uint4 r;
    r.x = sub2bf(a.x, b.x); r.y = sub2bf(a.y, b.y);
    r.z = sub2bf(a.z, b.z); r.w = sub2bf(a.w, b.w);
    return r;
}

// ---------------------------------------------------------------------------
// Fragment layout: element (m,k) at buf[((m_blk*S + s)*64 + lane)*8 + j],
// m = m_blk*32 + (lane&31), k = s*16 + (lane>>5)*8 + j. Same for B with n.

// Coalesced fragment pack for dense fp32 (used for f_atoms only): one block per
// 64-row tile; stage rows coalesced into LDS (bf16), then write fragments 16B/lane.
template<int S>
__global__ void __launch_bounds__(256)
pack_a_f32_c(const float* __restrict__ src, unsigned short* __restrict__ dst,
             int M, int K)
{
    __shared__ unsigned short sm[64 * 152];
    const int m0 = blockIdx.x * 64;
    const int r = threadIdx.x >> 2;
    const int q = threadIdx.x & 3;
    int mv = m0 + r; if (mv >= M) mv = M - 1;
    const float* rowF = src + (size_t)mv * K;
#pragma unroll
    for (int i = 0; i < (S * 4 + 3) / 4; ++i) {
        int c = q + i * 4;                    // chunk of 4 halfs
        if (c * 4 < S * 16) {
            unsigned short h[4];
#pragma unroll
            for (int e = 0; e < 4; ++e) {
                int k = c * 4 + e;
                h[e] = (k < K) ? f2bf(rowF[k]) : (unsigned short)0;
            }
            uint2 o;
            o.x = (unsigned int)h[0] | ((unsigned int)h[1] << 16);
            o.y = (unsigned int)h[2] | ((unsigned int)h[3] << 16);
            *(uint2*)&sm[r * 152 + c * 4] = o;
        }
    }
    __syncthreads();
    for (int j = threadIdx.x; j < 2 * S * 64; j += 256) {
        int lane = j & 63;
        int t = j >> 6;
        int s = t % S;
        int mb2 = t / S;
        uint4 v = *(const uint4*)&sm[(mb2 * 32 + (lane & 31)) * 152 + s * 16 + (lane >> 5) * 8];
        int m_blk = blockIdx.x * 2 + mb2;
        *(uint4*)&dst[((size_t)(m_blk * S + s) * 64 + lane) * 8] = v;
    }
}

__global__ void __launch_bounds__(256)
pack_b(const float* __restrict__ src1, const float* __restrict__ src2,
       unsigned short* __restrict__ dst, int K1, int S1, int K2, int SB)
{
    int g = blockIdx.x * 256 + threadIdx.x;
    if (g >= 10 * SB * 64) return;
    int lane = g & 63;
    int t = g >> 6;
    int s = t % SB;
    int n_blk = t / SB;
    int n = n_blk * 32 + (lane & 31);
    unsigned int w[4];
#pragma unroll
    for (int p = 0; p < 4; ++p) {
        unsigned short h[2];
#pragma unroll
        for (int e = 0; e < 2; ++e) {
            int kf = s * 16 + (lane >> 5) * 8 + p * 2 + e;
            float v = 0.0f;
            if (n < H) {
                if (s < S1) {
                    if (kf < K1) v = src1[(size_t)kf * H + n];
                } else {
                    int k2 = kf - S1 * 16;
                    if (k2 < K2) v = src2[(size_t)k2 * H + n];
                }
            }
            h[e] = f2bf(v);
        }
        w[p] = (unsigned int)h[0] | ((unsigned int)h[1] << 16);
    }
    *(uint4*)&dst[(size_t)g * 8] = make_uint4(w[0], w[1], w[2], w[3]);
}

// ---------------------------------------------------------------------------
// amsg[a][:] = sum_j maybe_relu(msg[a2b[a][j]][:]). One thread per 8 halfs.
template<int RELU>
__global__ void __launch_bounds__(256)
aggregate_row(const unsigned short* __restrict__ msg, const int* __restrict__ a2b,
              unsigned short* __restrict__ amsg, int n_atoms)
{
    int gid = blockIdx.x * 256 + threadIdx.x;
    int total = n_atoms * 38;
    if (gid >= total) return;
    int atom = gid / 38;
    int g8 = gid - atom * 38;
    const int* nb = a2b + atom * MAXNB;
    float sum[8] = {};
#pragma unroll
    for (int j = 0; j < MAXNB; ++j) {
        int b = nb[j];
        uint4 v = *(const uint4*)&msg[(size_t)b * RS + g8 * 8];
        if (RELU) v = relu4(v);
        unsigned int ww[4] = {v.x, v.y, v.z, v.w};
#pragma unroll
        for (int p = 0; p < 4; ++p) {
            sum[p * 2]     += bf2f((unsigned short)(ww[p] & 0xFFFFu));
            sum[p * 2 + 1] += bf2f((unsigned short)(ww[p] >> 16));
        }
    }
    unsigned int ow[4];
#pragma unroll
    for (int p = 0; p < 4; ++p)
        ow[p] = (unsigned int)f2bf(sum[p * 2]) | ((unsigned int)f2bf(sum[p * 2 + 1]) << 16);
    *(uint4*)&amsg[(size_t)atom * RS + g8 * 8] = make_uint4(ow[0], ow[1], ow[2], ow[3]);
}

// ---------------------------------------------------------------------------
// Fused MFMA GEMM, distance-2 B prefetch, row-per-thread gather staging.
// NOTE: no waves-per-EU cap — acc[5] needs 80 AGPRs + 40 VGPR prefetch regs;
// capping at 4 waves/EU (R10) forced accumulator spills (WRITE_SIZE 530 MB).
// MODE 0 (init): A = dense fp32 Adense staged fp32->bf16 in LDS. out = raw A@B.
// MODE 1 (mp):   A = LDS-staged (amsg[b2a[m]] - maybe_relu(msg[b2revb[m]])).
//                out = relu(A@B + inp_add).
// MODE 2 (cat):  A = [A1 packed | LDS-staged amsg rows]. out = relu(A@B + bias).
template<int S1, int S2, int SBL, int MODE, int RELUMSG>
__global__ void __launch_bounds__(256)
gemm_fused(const unsigned short* __restrict__ A1,
           const unsigned short* __restrict__ amsg,
           const unsigned short* __restrict__ msg,
           const int* __restrict__ b2a, const int* __restrict__ b2revb,
           const unsigned short* __restrict__ Bp,
           const float* __restrict__ bias,
           const unsigned short* __restrict__ inp_add,
           const float* __restrict__ Adense, int Kd,
           unsigned short* __restrict__ out, int M)
{
    __shared__ __align__(16) unsigned short smem[64 * ASTR]; // Ast / Cs union

    const int lane  = threadIdx.x & 63;
    const int w     = threadIdx.x >> 6;
    const int rbase = (w >> 1) * 32;
    const int cbase = (w & 1) * 160;
    const int mrow  = lane & 31;
    const int quad  = lane >> 5;
    const int m0    = blockIdx.x * 64;
    const int m_blk = blockIdx.x * 2 + (w >> 1);
    const int nblk0 = cbase >> 5;

    // ---- Stage A-tile: thread t owns row t>>2, chunk set (t&3)+4i.
    {
        const int r = threadIdx.x >> 2;
        const int q = threadIdx.x & 3;
        int mm = m0 + r;
        int mv = (mm < M) ? mm : 0;
        if (MODE == 0) {
            if (mm >= M) mv = M - 1;
            const float* rowF = Adense + (size_t)mv * Kd;
#pragma unroll
            for (int i = 0; i < (S2 * 4 + 3) / 4; ++i) {
                int c = q + i * 4;              // chunk of 4 halfs
                if (c * 4 < S2 * 16) {
                    unsigned short h[4];
#pragma unroll
                    for (int e = 0; e < 4; ++e) {
                        int k = c * 4 + e;
                        h[e] = (k < Kd) ? f2bf(rowF[k]) : (unsigned short)0;
                    }
                    uint2 o;
                    o.x = (unsigned int)h[0] | ((unsigned int)h[1] << 16);
                    o.y = (unsigned int)h[2] | ((unsigned int)h[3] << 16);
                    *(uint2*)&smem[r * ASTR + c * 4] = o;
                }
            }
            __syncthreads();
        } else if (MODE == 1 || MODE == 2) {
            const unsigned short* rowA;
            const unsigned short* rowM = nullptr;
            if (MODE == 1) {
                rowA = amsg + (size_t)b2a[mv] * RS;
                rowM = msg  + (size_t)b2revb[mv] * RS;
            } else {
                rowA = amsg + (size_t)mv * RS;
            }
#pragma unroll
            for (int i = 0; i < 10; ++i) {
                int c = q + i * 4;
                if (c < 38) {
                    uint4 o;
                    if (MODE == 1) {
                        uint4 va = *(const uint4*)(rowA + c * 8);
                        uint4 vm = *(const uint4*)(rowM + c * 8);
                        if (RELUMSG) vm = relu4(vm);
                        o = subpack4(va, vm);
                    } else {
                        o = *(const uint4*)(rowA + c * 8);
                    }
                    *(uint4*)&smem[r * ASTR + c * 8] = o;
                }
            }
            __syncthreads();
        }
    }

    f32x16 acc[5];
#pragma unroll
    for (int t = 0; t < 5; ++t)
#pragma unroll
        for (int i = 0; i < 16; ++i) acc[t][i] = 0.0f;

    const unsigned short* pa1 = (S1 > 0) ? (A1 + ((size_t)m_blk * S1 * 64 + lane) * 8) : nullptr;
    const unsigned short* pb  = Bp + ((size_t)nblk0 * SBL * 64 + lane) * 8;

    constexpr int STOT = S1 + S2;

    auto loadA = [&](int s) -> bf16x8 {
        if (s < S1) return *(const bf16x8*)(pa1 + (size_t)s * 512);
        return *(const bf16x8*)&smem[(rbase + mrow) * ASTR + (s - S1) * 16 + quad * 8];
    };

    bf16x8 b0[5], b1[5];
#pragma unroll
    for (int nt = 0; nt < 5; ++nt) b0[nt] = *(const bf16x8*)(pb + ((size_t)nt * SBL + 0) * 512);
    if (STOT > 1) {
#pragma unroll
        for (int nt = 0; nt < 5; ++nt) b1[nt] = *(const bf16x8*)(pb + ((size_t)nt * SBL + 1) * 512);
    }

#pragma unroll
    for (int s = 0; s < STOT; s += 2) {
        bf16x8 a = loadA(s);
        acc[0] = __builtin_amdgcn_mfma_f32_32x32x16_bf16(a, b0[0], acc[0], 0, 0, 0);
        acc[1] = __builtin_amdgcn_mfma_f32_32x32x16_bf16(a, b0[1], acc[1], 0, 0, 0);
        acc[2] = __builtin_amdgcn_mfma_f32_32x32x16_bf16(a, b0[2], acc[2], 0, 0, 0);
        acc[3] = __builtin_amdgcn_mfma_f32_32x32x16_bf16(a, b0[3], acc[3], 0, 0, 0);
        acc[4] = __builtin_amdgcn_mfma_f32_32x32x16_bf16(a, b0[4], acc[4], 0, 0, 0);
        if (s + 2 < STOT) {
#pragma unroll
            for (int nt = 0; nt < 5; ++nt) b0[nt] = *(const bf16x8*)(pb + ((size_t)nt * SBL + s + 2) * 512);
        }
        if (s + 1 < STOT) {
            bf16x8 a2 = loadA(s + 1);
            acc[0] = __builtin_amdgcn_mfma_f32_32x32x16_bf16(a2, b1[0], acc[0], 0, 0, 0);
            acc[1] = __builtin_amdgcn_mfma_f32_32x32x16_bf16(a2, b1[1], acc[1], 0, 0, 0);
            acc[2] = __builtin_amdgcn_mfma_f32_32x32x16_bf16(a2, b1[2], acc[2], 0, 0, 0);
            acc[3] = __builtin_amdgcn_mfma_f32_32x32x16_bf16(a2, b1[3], acc[3], 0, 0, 0);
            acc[4] = __builtin_amdgcn_mfma_f32_32x32x16_bf16(a2, b1[4], acc[4], 0, 0, 0);
            if (s + 3 < STOT) {
#pragma unroll
                for (int nt = 0; nt < 5; ++nt) b1[nt] = *(const bf16x8*)(pb + ((size_t)nt * SBL + s + 3) * 512);
            }
        }
    }

    __syncthreads();   // Ast reads done before Cs overwrites the union

    // C/D: col = lane&31 (+tile), row = (reg&3)+8*(reg>>2)+4*quad (+rbase). Raw.
#pragma unroll
    for (int nt = 0; nt < 5; ++nt) {
        int col = cbase + nt * 32 + mrow;
#pragma unroll
        for (int r = 0; r < 16; ++r) {
            int row = rbase + (r & 3) + 8 * (r >> 2) + 4 * quad;
            if (col < 308) smem[row * 308 + col] = f2bf(acc[nt][r]);
        }
    }
    __syncthreads();

    // Coalesced copy-out with fused epilogue math.
    for (int idx = threadIdx.x; idx < 64 * 76; idx += 256) {
        int row = idx / 76, gcol = idx - row * 76;
        int mm = m0 + row;
        if (mm >= M) continue;
        int c0 = gcol * 4;
        uint2 raw = *(const uint2*)&smem[row * 308 + c0];
        uint2 o;
        if (MODE == 0) {
            o = raw;   // raw pre-activation store (relu applied at consumers)
        } else {
            unsigned short h[4] = {(unsigned short)(raw.x & 0xFFFFu), (unsigned short)(raw.x >> 16),
                                   (unsigned short)(raw.y & 0xFFFFu), (unsigned short)(raw.y >> 16)};
            float v[4];
#pragma unroll
            for (int e = 0; e < 4; ++e) v[e] = bf2f(h[e]);
            if (MODE == 1) {
                uint2 iv = *(const uint2*)&inp_add[(size_t)mm * RS + c0];
                v[0] += bf2f((unsigned short)(iv.x & 0xFFFFu));
                v[1] += bf2f((unsigned short)(iv.x >> 16));
                v[2] += bf2f((unsigned short)(iv.y & 0xFFFFu));
                v[3] += bf2f((unsigned short)(iv.y >> 16));
            } else {
#pragma unroll
                for (int e = 0; e < 4; ++e) v[e] += (c0 + e < H) ? bias[c0 + e] : 0.0f;
            }
#pragma unroll
            for (int e = 0; e < 4; ++e) h[e] = f2bf(fmaxf(v[e], 0.0f));
            o.x = (unsigned int)h[0] | ((unsigned int)h[1] << 16);
            o.y = (unsigned int)h[2] | ((unsigned int)h[3] << 16);
        }
        *(uint2*)&out[(size_t)mm * RS + c0] = o;
    }
}

// ---------------------------------------------------------------------------
__global__ void __launch_bounds__(128)
segmean_kernel(const unsigned short* __restrict__ ah,
               const int* __restrict__ mol_id, int n_atoms,
               float* __restrict__ out)
{
    int m = blockIdx.x;
    int lo = 0, hi = n_atoms;
    while (lo < hi) { int mid = (lo + hi) >> 1; if (mol_id[mid] < m) lo = mid + 1; else hi = mid; }
    int start = lo;
    hi = n_atoms;
    while (lo < hi) { int mid = (lo + hi) >> 1; if (mol_id[mid] < m + 1) lo = mid + 1; else hi = mid; }
    int end = lo;

    int c = threadIdx.x;
    float a0 = 0.f, a1 = 0.f, a2 = 0.f;
    for (int a = start; a < end; ++a) {
        const unsigned short* row = ah + (size_t)a * RS;
        a0 += bf2f(row[c]);
        a1 += bf2f(row[c + 128]);
        if (c < H - 256) a2 += bf2f(row[c + 256]);
    }
    float inv = (end > start) ? 1.0f / (float)(end - start) : 0.0f;
    float* orow = out + (size_t)m * H;
    orow[c] = a0 * inv;
    orow[c + 128] = a1 * inv;
    if (c < H - 256) orow[c + 256] = a2 * inv;
}

// ---------------------------------------------------------------------------
extern "C" void kernel_launch(void* const* d_in, const int* in_sizes, int n_in,
                              void* d_out, int out_size, void* d_ws, size_t ws_size,
                              hipStream_t stream)
{
    const float* f_atoms = (const float*)d_in[0];
    const float* f_bonds = (const float*)d_in[1];
    const int*   a2b     = (const int*)d_in[2];
    const int*   b2a     = (const int*)d_in[3];
    const int*   b2revb  = (const int*)d_in[4];
    const int*   mol_id  = (const int*)d_in[5];
    const float* W_i     = (const float*)d_in[7];
    const float* W_h     = (const float*)d_in[8];
    const float* W_o     = (const float*)d_in[9];
    const float* b_o     = (const float*)d_in[10];

    const int n_atoms   = in_sizes[5];
    const int n_bonds   = in_sizes[3];
    const int atom_fdim = in_sizes[0] / n_atoms;   // 133
    const int bond_fdim = in_sizes[1] / n_bonds;   // 147
    const int n_mols    = out_size / H;            // 2000

    const int gBonds = (n_bonds + 63) / 64;
    const int gAtoms = (n_atoms + 63) / 64;
    const int MBa = 2 * gAtoms;

    const size_t bondsRS = (size_t)n_bonds * RS;
    const size_t atomsRS = (size_t)n_atoms * RS;
    const size_t fapSz   = (size_t)MBa * 9 * 512;
    const size_t wihSz   = 10 * 30 * 512;
    const size_t woSz    = 10 * 29 * 512;
    const size_t wh19Sz  = 10 * 19 * 512;

    // Layout (halfs): inp | msgB | amsg | wih | wo | wh19 | ah
    // Overlays: iter-2 mp writes message2 in-place over inp (audited safe);
    //           fap overlays inp after final aggregate.
    unsigned short* inp  = (unsigned short*)d_ws;
    unsigned short* msgB = inp  + bondsRS;
    unsigned short* amsg = msgB + bondsRS;
    unsigned short* wih  = amsg + atomsRS;
    unsigned short* wo   = wih  + wihSz;
    unsigned short* wh19 = wo   + woSz;
    unsigned short* ah   = wh19 + wh19Sz;
    unsigned short* fap  = inp;          // fap (14.4 MB) fits in inp (60.8 MB)

    dim3 blk(256);
    const int aggBlocks = (n_atoms * 38 + 255) / 256;

    pack_b<<<(10 * 30 * 64 + 255) / 256, blk, 0, stream>>>(W_i, W_h, wih, bond_fdim, 10, H, 30);
    pack_b<<<(10 * 19 * 64 + 255) / 256, blk, 0, stream>>>(W_h, W_h, wh19, H, 19, 0, 19);
    pack_b<<<(10 * 29 * 64 + 255) / 256, blk, 0, stream>>>(W_o, W_o + (size_t)atom_fdim * H, wo,
                                                           atom_fdim, 9, H, 29);

    // init: inp = f_bonds @ W_i  (raw; f_bonds staged fp32->bf16 in-kernel)
    gemm_fused<0, 10, 30, 0, 0><<<gBonds, blk, 0, stream>>>(
        nullptr, nullptr, nullptr, nullptr, nullptr, wih, nullptr, nullptr,
        f_bonds, bond_fdim, inp, n_bonds);

    // iter 1: message1 = relu(inp + (amsg[b2a] - relu(inp[b2revb])) @ W_h) -> msgB
    aggregate_row<1><<<aggBlocks, blk, 0, stream>>>(inp, a2b, amsg, n_atoms);
    gemm_fused<0, 19, 19, 1, 1><<<gBonds, blk, 0, stream>>>(
        nullptr, amsg, inp, b2a, b2revb, wh19, nullptr, inp, nullptr, 0, msgB, n_bonds);

    // iter 2: message2 -> inp (in-place; inp only read by this kernel's epilogue)
    aggregate_row<0><<<aggBlocks, blk, 0, stream>>>(msgB, a2b, amsg, n_atoms);
    gemm_fused<0, 19, 19, 1, 0><<<gBonds, blk, 0, stream>>>(
        nullptr, amsg, msgB, b2a, b2revb, wh19, nullptr, inp, nullptr, 0, inp, n_bonds);

    // final aggregation from message2
    aggregate_row<0><<<aggBlocks, blk, 0, stream>>>(inp, a2b, amsg, n_atoms);

    // f_atoms pack, coalesced (overlays inp region — dead after final aggregate)
    pack_a_f32_c<9><<<gAtoms, blk, 0, stream>>>(f_atoms, fap, n_atoms, atom_fdim);

    // cat GEMM: ah = relu([f_atoms | amsg] @ W_o + b_o)
    gemm_fused<9, 19, 29, 2, 0><<<gAtoms, blk, 0, stream>>>(
        fap, amsg, nullptr, nullptr, nullptr, wo, b_o, nullptr, nullptr, 0, ah, n_atoms);

    segmean_kernel<<<n_mols, dim3(128), 0, stream>>>(ah, mol_id, n_atoms, (float*)d_out);
}